// Round 9
// baseline (2936.025 us; speedup 1.0000x reference)
//
#include <hip/hip_runtime.h>
#include <hip/hip_bf16.h>

#define M_DIM 8192
#define N_DIM 4096
#define K_DIM 4096

using bf16x8 = __attribute__((ext_vector_type(8))) short;
using f32x4  = __attribute__((ext_vector_type(4))) float;

// ---------- fp32 -> bf16 (RNE via bit math) ----------
__device__ __forceinline__ unsigned short f2bf(float f) {
    unsigned int u = __float_as_uint(f);
    unsigned int r = u + 0x7fffu + ((u >> 16) & 1u);
    return (unsigned short)(r >> 16);
}

// Single fused conversion: x (n4x float4s) then w (n4w float4s) into ws.
__global__ void cvt_both_f32_to_bf16(const float* __restrict__ x,
                                     const float* __restrict__ w,
                                     unsigned short* __restrict__ ws,
                                     int n4x, int n4w) {
    int i = blockIdx.x * blockDim.x + threadIdx.x;
    const int stride = gridDim.x * blockDim.x;
    const int total = n4x + n4w;
    uint2* dx = reinterpret_cast<uint2*>(ws);
    uint2* dw = reinterpret_cast<uint2*>(ws) + n4x;
    for (; i < total; i += stride) {
        const bool isX = i < n4x;
        const float4* s4 = isX ? reinterpret_cast<const float4*>(x)
                               : reinterpret_cast<const float4*>(w);
        const int j = isX ? i : i - n4x;
        float4 v = s4[j];
        uint2 o;
        o.x = (unsigned)f2bf(v.x) | ((unsigned)f2bf(v.y) << 16);
        o.y = (unsigned)f2bf(v.z) | ((unsigned)f2bf(v.w) << 16);
        (isX ? dx : dw)[j] = o;
    }
}

// ---------- async global->LDS, 16B per lane ----------
__device__ __forceinline__ void gload16(const unsigned short* g, char* l) {
    __builtin_amdgcn_global_load_lds(
        (const __attribute__((address_space(1))) void*)g,
        (__attribute__((address_space(3))) void*)l, 16, 0, 0);
}

// ============================================================================
// 256x256 bf16 MFMA GEMM — round 9: BK=32, 64 KiB LDS -> 2 blocks/CU (TLP).
// R3-R8 established the intra-block schedule plateau (~53% MfmaUtil across 4
// sync structures). This round halves the K-step so two blocks co-reside per
// CU: one block's barrier/stall/epilogue hides under the other's MFMA, and
// all 512 blocks are resident (no sequential pass boundary).
//
// LDS (64 KiB): A[2 buf][256 rows][32 k]  bf16 (16 KiB/buf), rows = M-rows
//               B[2 buf][256 rows][32 k]  bf16, rows = N-cols
// Row stride 64 B. Swizzle (derived for 64B rows, verified 2-way-free per
// quarter-wave): store at (row, slot): global k-chunk slot^((row>>1)&3);
// staging lane covers row W+(lane>>2), slot lane&3 -> src chunk
// (lane&3)^((lane>>3)&3) (W multiple of 16 makes it wave-uniform).
// Read (16x16x32 MFMA, lane=(lr,t4)): slot = t4 ^ ((lr>>1)&3).
//
// Per K-tile (one barrier): {12 ds_read (8 A-frags + 4 B-frags); 4 gload_lds
// staging t+1 -> nbuf; 32 MFMA (all-independent chains); vmcnt(0); barrier}.
// Ledger: stage(t+1) lands before its reads (vmcnt(0) this tile); nbuf slot
// dead (tile t-1's reads consumed by t-1's MFMA before t-1's barrier).
// Tail stages wrapped kt=0 (dummy) into the dead buffer.
// ============================================================================
__global__ __launch_bounds__(512, 4) void gemm_bf16_256_bk32(
        const unsigned short* __restrict__ xb,   // [M,K] bf16 bits
        const unsigned short* __restrict__ wb,   // [N,K] bf16 bits
        const float* __restrict__ bias,          // [N]
        float* __restrict__ out) {               // [M,N]
    extern __shared__ char lds[];
    char* ldsA = lds;           // [2 buf][16384 B]
    char* ldsB = lds + 32768;   // [2 buf][16384 B]

    // L2-aware XCD chunk map (round 4: FETCH 549->201 MB)
    const int bid = blockIdx.x;
    const int xcd = bid & 7;
    const int c   = bid >> 3;                 // 0..63
    const int tm  = (xcd >> 1) * 8 + (c & 7); // 0..31
    const int tn  = (xcd & 1) * 8 + (c >> 3); // 0..15
    const int r0 = tm * 256;
    const int c0 = tn * 256;

    const int tid  = threadIdx.x;
    const int lane = tid & 63;
    const int wave = tid >> 6;        // 0..7
    const int wm = wave >> 2;         // 0..1  (128-row half)
    const int wn = wave & 3;          // 0..3  (64-col strip)
    const int lr = lane & 15;
    const int t4 = lane >> 4;

    // --- ds_read offsets (bytes), 64B-row swizzle ---
    int aRd[8], bRd[4];
    const int slot = (t4 ^ ((lr >> 1) & 3)) << 4;
#pragma unroll
    for (int m = 0; m < 8; ++m)
        aRd[m] = (wm * 128 + m * 16 + lr) * 64 + slot;
#pragma unroll
    for (int n = 0; n < 4; ++n)
        bRd[n] = (wn * 64 + n * 16 + lr) * 64 + slot;

    // --- staging: wave-uniform LDS dest (HW adds lane*16); source chunk
    //     pre-swizzled: chunk = (lane&3) ^ ((lane>>3)&3) ---
    const int chunk = ((lane & 3) ^ ((lane >> 3) & 3)) * 8;   // elem offset
    int aSrcB[2], bSrcB[2], dstOff[2];
#pragma unroll
    for (int l = 0; l < 2; ++l) {
        const int W = wave * 32 + l * 16;                 // row base 0..240
        aSrcB[l] = (r0 + W + (lane >> 2)) * K_DIM + chunk;
        bSrcB[l] = (c0 + W + (lane >> 2)) * K_DIM + chunk;
        dstOff[l] = W * 64;                               // wave-uniform
    }

    auto STAGE = [&](int kt, int nb) {
#pragma unroll
        for (int l = 0; l < 2; ++l) {
            gload16(xb + aSrcB[l] + kt * 32, ldsA + nb * 16384 + dstOff[l]);
            gload16(wb + bSrcB[l] + kt * 32, ldsB + nb * 16384 + dstOff[l]);
        }
    };

    f32x4 acc[8][4];
#pragma unroll
    for (int i = 0; i < 8; ++i)
#pragma unroll
        for (int j = 0; j < 4; ++j)
            acc[i][j] = (f32x4){0.f, 0.f, 0.f, 0.f};

    bf16x8 av[8], bv[4];

    const int NT = K_DIM / 32;   // 128

    // --- prologue: stage t0 -> buf0 ---
    STAGE(0, 0);
    asm volatile("s_waitcnt vmcnt(0)\n\ts_barrier" ::: "memory");

    for (int t = 0; t < NT; ++t) {
        const int buf = t & 1, nbuf = buf ^ 1;
        const int kt1 = (t + 1) & (NT - 1);   // last tile: dummy re-stage of 0
        // reads of tile t
#pragma unroll
        for (int m = 0; m < 8; ++m)
            av[m] = *(const bf16x8*)(ldsA + buf * 16384 + aRd[m]);
#pragma unroll
        for (int n = 0; n < 4; ++n)
            bv[n] = *(const bf16x8*)(ldsB + buf * 16384 + bRd[n]);
        // stage tile t+1
        STAGE(kt1, nbuf);
        // 32 independent MFMA chains
        __builtin_amdgcn_s_setprio(1);
#pragma unroll
        for (int m = 0; m < 8; ++m)
#pragma unroll
            for (int n = 0; n < 4; ++n)
                acc[m][n] = __builtin_amdgcn_mfma_f32_16x16x32_bf16(
                    av[m], bv[n], acc[m][n], 0, 0, 0);
        __builtin_amdgcn_s_setprio(0);
        asm volatile("s_waitcnt vmcnt(0)\n\ts_barrier" ::: "memory");
    }

    // --- epilogue: C/D layout col=lane&15, row=t4*4+j ---
#pragma unroll
    for (int ni = 0; ni < 4; ++ni) {
        const int col = c0 + wn * 64 + ni * 16 + lr;
        const float bvs = bias[col];
#pragma unroll
        for (int mi = 0; mi < 8; ++mi) {
            const int row0 = r0 + wm * 128 + mi * 16 + t4 * 4;
#pragma unroll
            for (int j = 0; j < 4; ++j)
                out[(row0 + j) * N_DIM + col] = acc[mi][ni][j] + bvs;
        }
    }
}

// ============================================================================
// Proven round-1 128x128 kernel — runtime fallback if dynamic LDS
// cannot be enabled.
// ============================================================================
__global__ __launch_bounds__(256) void gemm_bf16_mfma(
        const unsigned short* __restrict__ xb,
        const unsigned short* __restrict__ wb,
        const float* __restrict__ bias,
        float* __restrict__ out) {
    __shared__ unsigned short sA[128 * 64];
    __shared__ unsigned short sB[128 * 64];

    const int nwg = (M_DIM / 128) * (N_DIM / 128);
    const int q = nwg / 8;
    int bid = blockIdx.x;
    int bid2 = (bid & 7) * q + (bid >> 3);
    const int tm = bid2 & 63;
    const int tn = bid2 >> 6;
    const int r0 = tm * 128;
    const int c0 = tn * 128;

    const int tid  = threadIdx.x;
    const int lane = tid & 63;
    const int wave = tid >> 6;
    const int wr = wave >> 1;
    const int wc = wave & 1;
    const int lr = lane & 15;
    const int t  = lane >> 4;

    int aoff[2][4], boff[2][4];
#pragma unroll
    for (int m = 0; m < 4; ++m) {
        int rowA = wr * 64 + m * 16 + lr;
        int swA  = (rowA & 7) << 4;
        int rowB = wc * 64 + m * 16 + lr;
        int swB  = (rowB & 7) << 4;
#pragma unroll
        for (int kk = 0; kk < 2; ++kk) {
            int cb = kk * 64 + t * 16;
            aoff[kk][m] = rowA * 64 + ((cb ^ swA) >> 1);
            boff[kk][m] = rowB * 64 + ((cb ^ swB) >> 1);
        }
    }

    const int sRow   = lane >> 3;
    const int sChunk = (lane & 7) ^ sRow;
    int aSrc[4], bSrc[4];
    char* ldsA[4];
    char* ldsB[4];
#pragma unroll
    for (int r = 0; r < 4; ++r) {
        int row = r * 32 + wave * 8 + sRow;
        aSrc[r] = (r0 + row) * K_DIM + sChunk * 8;
        bSrc[r] = (c0 + row) * K_DIM + sChunk * 8;
        ldsA[r] = (char*)sA + (r * 4 + wave) * 1024;
        ldsB[r] = (char*)sB + (r * 4 + wave) * 1024;
    }

    f32x4 acc[4][4];
#pragma unroll
    for (int m = 0; m < 4; ++m)
#pragma unroll
        for (int n = 0; n < 4; ++n)
            acc[m][n] = (f32x4){0.f, 0.f, 0.f, 0.f};

    for (int kt = 0; kt < K_DIM / 64; ++kt) {
        const int ko = kt * 64;
#pragma unroll
        for (int r = 0; r < 4; ++r) {
            gload16(xb + aSrc[r] + ko, ldsA[r]);
            gload16(wb + bSrc[r] + ko, ldsB[r]);
        }
        __syncthreads();
#pragma unroll
        for (int kk = 0; kk < 2; ++kk) {
            bf16x8 av[4], bv[4];
#pragma unroll
            for (int m = 0; m < 4; ++m)
                av[m] = *reinterpret_cast<const bf16x8*>(sA + aoff[kk][m]);
#pragma unroll
            for (int n = 0; n < 4; ++n)
                bv[n] = *reinterpret_cast<const bf16x8*>(sB + boff[kk][n]);
#pragma unroll
            for (int m = 0; m < 4; ++m)
#pragma unroll
                for (int n = 0; n < 4; ++n)
                    acc[m][n] = __builtin_amdgcn_mfma_f32_16x16x32_bf16(
                        av[m], bv[n], acc[m][n], 0, 0, 0);
        }
        __syncthreads();
    }

#pragma unroll
    for (int n = 0; n < 4; ++n) {
        const int col = c0 + wc * 64 + n * 16 + lr;
        const float bv = bias[col];
#pragma unroll
        for (int m = 0; m < 4; ++m) {
            const int row0 = r0 + wr * 64 + m * 16 + t * 4;
#pragma unroll
            for (int j = 0; j < 4; ++j)
                out[(row0 + j) * N_DIM + col] = acc[m][n][j] + bv;
        }
    }
}

// ---------- fp32 fallback (only if ws too small) ----------
__global__ void fallback_gemm_f32(const float* __restrict__ x,
                                  const float* __restrict__ w,
                                  const float* __restrict__ bias,
                                  float* __restrict__ out) {
    __shared__ float sX[2][4096];
    const int tid = threadIdx.x;
    const int col = blockIdx.x * 256 + tid;
    const int row0 = blockIdx.y * 2;
    for (int i = tid * 4; i < 8192; i += 1024) {
        int r = i >> 12, c = i & 4095;
        *(float4*)&sX[r][c] = *(const float4*)&x[(size_t)(row0 + r) * 4096 + c];
    }
    __syncthreads();
    const float4* wrow = (const float4*)&w[(size_t)col * 4096];
    float a0 = 0.f, a1 = 0.f;
    for (int k4 = 0; k4 < 1024; ++k4) {
        float4 wv = wrow[k4];
        int k = k4 << 2;
        a0 += wv.x * sX[0][k] + wv.y * sX[0][k + 1] + wv.z * sX[0][k + 2] + wv.w * sX[0][k + 3];
        a1 += wv.x * sX[1][k] + wv.y * sX[1][k + 1] + wv.z * sX[1][k + 2] + wv.w * sX[1][k + 3];
    }
    float bv = bias[col];
    out[(size_t)row0 * 4096 + col] = a0 + bv;
    out[(size_t)(row0 + 1) * 4096 + col] = a1 + bv;
}

extern "C" void kernel_launch(void* const* d_in, const int* in_sizes, int n_in,
                              void* d_out, int out_size, void* d_ws, size_t ws_size,
                              hipStream_t stream) {
    const float* x    = (const float*)d_in[0];
    const float* w    = (const float*)d_in[1];
    const float* bias = (const float*)d_in[2];
    float* out = (float*)d_out;

    const size_t nX = (size_t)M_DIM * K_DIM;
    const size_t nW = (size_t)N_DIM * K_DIM;
    const size_t need = (nX + nW) * sizeof(unsigned short);

    if (ws_size >= need) {
        unsigned short* xb = (unsigned short*)d_ws;
        unsigned short* wb = xb + nX;
        cvt_both_f32_to_bf16<<<3072, 256, 0, stream>>>(
            x, w, (unsigned short*)d_ws, (int)(nX / 4), (int)(nW / 4));
        hipError_t e = hipFuncSetAttribute(
            (const void*)gemm_bf16_256_bk32,
            hipFuncAttributeMaxDynamicSharedMemorySize, 65536);
        if (e == hipSuccess) {
            gemm_bf16_256_bk32<<<(M_DIM / 256) * (N_DIM / 256), 512, 65536, stream>>>(
                xb, wb, bias, out);
        } else {
            gemm_bf16_mfma<<<(M_DIM / 128) * (N_DIM / 128), 256, 0, stream>>>(
                xb, wb, bias, out);
        }
    } else {
        fallback_gemm_f32<<<dim3(N_DIM / 256, M_DIM / 2), 256, 0, stream>>>(x, w, bias, out);
    }
}

// Round 10
// 299.637 us; speedup vs baseline: 9.7986x; 9.7986x over previous
//
#include <hip/hip_runtime.h>
#include <hip/hip_bf16.h>

#define M_DIM 8192
#define N_DIM 4096
#define K_DIM 4096

using bf16x8 = __attribute__((ext_vector_type(8))) short;
using f32x4  = __attribute__((ext_vector_type(4))) float;

// ---------- fp32 -> bf16 (RNE via bit math) ----------
__device__ __forceinline__ unsigned short f2bf(float f) {
    unsigned int u = __float_as_uint(f);
    unsigned int r = u + 0x7fffu + ((u >> 16) & 1u);
    return (unsigned short)(r >> 16);
}

// Single fused conversion: x (n4x float4s) then w (n4w float4s) into ws.
__global__ void cvt_both_f32_to_bf16(const float* __restrict__ x,
                                     const float* __restrict__ w,
                                     unsigned short* __restrict__ ws,
                                     int n4x, int n4w) {
    int i = blockIdx.x * blockDim.x + threadIdx.x;
    const int stride = gridDim.x * blockDim.x;
    const int total = n4x + n4w;
    uint2* dx = reinterpret_cast<uint2*>(ws);
    uint2* dw = reinterpret_cast<uint2*>(ws) + n4x;
    for (; i < total; i += stride) {
        const bool isX = i < n4x;
        const float4* s4 = isX ? reinterpret_cast<const float4*>(x)
                               : reinterpret_cast<const float4*>(w);
        const int j = isX ? i : i - n4x;
        float4 v = s4[j];
        uint2 o;
        o.x = (unsigned)f2bf(v.x) | ((unsigned)f2bf(v.y) << 16);
        o.y = (unsigned)f2bf(v.z) | ((unsigned)f2bf(v.w) << 16);
        (isX ? dx : dw)[j] = o;
    }
}

// ---------- async global->LDS, 16B per lane ----------
__device__ __forceinline__ void gload16(const unsigned short* g, char* l) {
    __builtin_amdgcn_global_load_lds(
        (const __attribute__((address_space(1))) void*)g,
        (__attribute__((address_space(3))) void*)l, 16, 0, 0);
}

// ============================================================================
// 128x256 bf16 MFMA GEMM, BK=32, 48 KiB LDS -> 2 blocks/CU (TLP).
// Round 10: R9's TLP idea with register math fixed. Per wave output 64x64 ->
// acc = 64 VGPR; total ~120 < 128 cap at 4 waves/SIMD (R9 failed because
// acc alone was 128 -> hipcc demoted the array to scratch, 14.8 GB traffic).
//
// LDS: A[2 buf][128 rows][32 k] bf16 (8 KiB/buf), B[2 buf][256 rows][32 k]
// (16 KiB/buf). Row stride 64 B. Swizzle (PROVEN in R9: absmax 0.5,
// conflicts 0): store slot lane&3 of row W+(lane>>2) holds global k-chunk
// (lane&3)^((lane>>3)&3); read slot = t4 ^ ((lr>>1)&3).
//
// Per K-tile (one barrier): {8 ds_read (4 A + 4 B frags); 3 gload_lds staging
// t+1 -> nbuf (1 A + 2 B); 16 MFMA; vmcnt(0); barrier}. The co-resident
// second block fills the vmcnt/barrier stall (m114 co-scheduling).
// Tail stages wrapped kt=0 (dummy) into the dead buffer (R9-proven).
// ============================================================================
__global__ __launch_bounds__(512, 4) void gemm_bf16_128x256_bk32(
        const unsigned short* __restrict__ xb,   // [M,K] bf16 bits
        const unsigned short* __restrict__ wb,   // [N,K] bf16 bits
        const float* __restrict__ bias,          // [N]
        float* __restrict__ out) {               // [M,N]
    extern __shared__ char lds[];
    char* ldsA = lds;           // [2 buf][8192 B]
    char* ldsB = lds + 16384;   // [2 buf][16384 B]

    // L2-aware XCD chunk map, bijective over 64 tm x 16 tn (1024 blocks):
    // xcd -> chunk (xcd>>1, xcd&1) of 16tm x 8tn.
    const int bid = blockIdx.x;
    const int xcd = bid & 7;
    const int c   = bid >> 3;                  // 0..127
    const int tm  = (xcd >> 1) * 16 + (c & 15); // 0..63
    const int tn  = (xcd & 1) * 8 + (c >> 4);   // 0..15
    const int r0 = tm * 128;
    const int c0 = tn * 256;

    const int tid  = threadIdx.x;
    const int lane = tid & 63;
    const int wave = tid >> 6;        // 0..7
    const int wm = wave >> 2;         // 0..1  (64-row half of 128)
    const int wn = wave & 3;          // 0..3  (64-col strip of 256)
    const int lr = lane & 15;
    const int t4 = lane >> 4;

    // --- ds_read offsets (bytes), 64B-row swizzle (R9-proven) ---
    int aRd[4], bRd[4];
    const int slot = (t4 ^ ((lr >> 1) & 3)) << 4;
#pragma unroll
    for (int m = 0; m < 4; ++m)
        aRd[m] = (wm * 64 + m * 16 + lr) * 64 + slot;
#pragma unroll
    for (int n = 0; n < 4; ++n)
        bRd[n] = (wn * 64 + n * 16 + lr) * 64 + slot;

    // --- staging: wave-uniform LDS dest (HW adds lane*16); source chunk
    //     pre-swizzled: chunk = (lane&3) ^ ((lane>>3)&3) (R9-proven) ---
    const int chunk = ((lane & 3) ^ ((lane >> 3) & 3)) * 8;   // elem offset
    const int aSrc  = (r0 + wave * 16 + (lane >> 2)) * K_DIM + chunk;
    int bSrc[2];
#pragma unroll
    for (int l = 0; l < 2; ++l)
        bSrc[l] = (c0 + wave * 32 + l * 16 + (lane >> 2)) * K_DIM + chunk;

    auto STAGE = [&](int kt, int nb) {
        gload16(xb + aSrc + kt * 32, ldsA + nb * 8192 + wave * 1024);
#pragma unroll
        for (int l = 0; l < 2; ++l)
            gload16(wb + bSrc[l] + kt * 32,
                    ldsB + nb * 16384 + (wave * 32 + l * 16) * 64);
    };

    f32x4 acc[4][4];
#pragma unroll
    for (int i = 0; i < 4; ++i)
#pragma unroll
        for (int j = 0; j < 4; ++j)
            acc[i][j] = (f32x4){0.f, 0.f, 0.f, 0.f};

    bf16x8 av[4], bv[4];

    const int NT = K_DIM / 32;   // 128

    // --- prologue: stage t0 -> buf0 ---
    STAGE(0, 0);
    asm volatile("s_waitcnt vmcnt(0)\n\ts_barrier" ::: "memory");

    for (int t = 0; t < NT; ++t) {
        const int buf = t & 1, nbuf = buf ^ 1;
        const int kt1 = (t + 1) & (NT - 1);   // last tile: dummy re-stage of 0
        // reads of tile t
#pragma unroll
        for (int m = 0; m < 4; ++m)
            av[m] = *(const bf16x8*)(ldsA + buf * 8192 + aRd[m]);
#pragma unroll
        for (int n = 0; n < 4; ++n)
            bv[n] = *(const bf16x8*)(ldsB + buf * 16384 + bRd[n]);
        // stage tile t+1
        STAGE(kt1, nbuf);
        // 16 independent MFMA chains
        __builtin_amdgcn_s_setprio(1);
#pragma unroll
        for (int m = 0; m < 4; ++m)
#pragma unroll
            for (int n = 0; n < 4; ++n)
                acc[m][n] = __builtin_amdgcn_mfma_f32_16x16x32_bf16(
                    av[m], bv[n], acc[m][n], 0, 0, 0);
        __builtin_amdgcn_s_setprio(0);
        asm volatile("s_waitcnt vmcnt(0)\n\ts_barrier" ::: "memory");
    }

    // --- epilogue: C/D layout col=lane&15, row=t4*4+j ---
#pragma unroll
    for (int ni = 0; ni < 4; ++ni) {
        const int col = c0 + wn * 64 + ni * 16 + lr;
        const float bvs = bias[col];
#pragma unroll
        for (int mi = 0; mi < 4; ++mi) {
            const int row0 = r0 + wm * 64 + mi * 16 + t4 * 4;
#pragma unroll
            for (int j = 0; j < 4; ++j)
                out[(row0 + j) * N_DIM + col] = acc[mi][ni][j] + bvs;
        }
    }
}

// ============================================================================
// Proven round-1 128x128 kernel — runtime fallback if dynamic LDS
// cannot be enabled.
// ============================================================================
__global__ __launch_bounds__(256) void gemm_bf16_mfma(
        const unsigned short* __restrict__ xb,
        const unsigned short* __restrict__ wb,
        const float* __restrict__ bias,
        float* __restrict__ out) {
    __shared__ unsigned short sA[128 * 64];
    __shared__ unsigned short sB[128 * 64];

    const int nwg = (M_DIM / 128) * (N_DIM / 128);
    const int q = nwg / 8;
    int bid = blockIdx.x;
    int bid2 = (bid & 7) * q + (bid >> 3);
    const int tm = bid2 & 63;
    const int tn = bid2 >> 6;
    const int r0 = tm * 128;
    const int c0 = tn * 128;

    const int tid  = threadIdx.x;
    const int lane = tid & 63;
    const int wave = tid >> 6;
    const int wr = wave >> 1;
    const int wc = wave & 1;
    const int lr = lane & 15;
    const int t  = lane >> 4;

    int aoff[2][4], boff[2][4];
#pragma unroll
    for (int m = 0; m < 4; ++m) {
        int rowA = wr * 64 + m * 16 + lr;
        int swA  = (rowA & 7) << 4;
        int rowB = wc * 64 + m * 16 + lr;
        int swB  = (rowB & 7) << 4;
#pragma unroll
        for (int kk = 0; kk < 2; ++kk) {
            int cb = kk * 64 + t * 16;
            aoff[kk][m] = rowA * 64 + ((cb ^ swA) >> 1);
            boff[kk][m] = rowB * 64 + ((cb ^ swB) >> 1);
        }
    }

    const int sRow   = lane >> 3;
    const int sChunk = (lane & 7) ^ sRow;
    int aSrc[4], bSrc[4];
    char* ldsA[4];
    char* ldsB[4];
#pragma unroll
    for (int r = 0; r < 4; ++r) {
        int row = r * 32 + wave * 8 + sRow;
        aSrc[r] = (r0 + row) * K_DIM + sChunk * 8;
        bSrc[r] = (c0 + row) * K_DIM + sChunk * 8;
        ldsA[r] = (char*)sA + (r * 4 + wave) * 1024;
        ldsB[r] = (char*)sB + (r * 4 + wave) * 1024;
    }

    f32x4 acc[4][4];
#pragma unroll
    for (int m = 0; m < 4; ++m)
#pragma unroll
        for (int n = 0; n < 4; ++n)
            acc[m][n] = (f32x4){0.f, 0.f, 0.f, 0.f};

    for (int kt = 0; kt < K_DIM / 64; ++kt) {
        const int ko = kt * 64;
#pragma unroll
        for (int r = 0; r < 4; ++r) {
            gload16(xb + aSrc[r] + ko, ldsA[r]);
            gload16(wb + bSrc[r] + ko, ldsB[r]);
        }
        __syncthreads();
#pragma unroll
        for (int kk = 0; kk < 2; ++kk) {
            bf16x8 av[4], bv[4];
#pragma unroll
            for (int m = 0; m < 4; ++m)
                av[m] = *reinterpret_cast<const bf16x8*>(sA + aoff[kk][m]);
#pragma unroll
            for (int n = 0; n < 4; ++n)
                bv[n] = *reinterpret_cast<const bf16x8*>(sB + boff[kk][n]);
#pragma unroll
            for (int m = 0; m < 4; ++m)
#pragma unroll
                for (int n = 0; n < 4; ++n)
                    acc[m][n] = __builtin_amdgcn_mfma_f32_16x16x32_bf16(
                        av[m], bv[n], acc[m][n], 0, 0, 0);
        }
        __syncthreads();
    }

#pragma unroll
    for (int n = 0; n < 4; ++n) {
        const int col = c0 + wc * 64 + n * 16 + lr;
        const float bv = bias[col];
#pragma unroll
        for (int m = 0; m < 4; ++m) {
            const int row0 = r0 + wr * 64 + m * 16 + t * 4;
#pragma unroll
            for (int j = 0; j < 4; ++j)
                out[(row0 + j) * N_DIM + col] = acc[m][n][j] + bv;
        }
    }
}

// ---------- fp32 fallback (only if ws too small) ----------
__global__ void fallback_gemm_f32(const float* __restrict__ x,
                                  const float* __restrict__ w,
                                  const float* __restrict__ bias,
                                  float* __restrict__ out) {
    __shared__ float sX[2][4096];
    const int tid = threadIdx.x;
    const int col = blockIdx.x * 256 + tid;
    const int row0 = blockIdx.y * 2;
    for (int i = tid * 4; i < 8192; i += 1024) {
        int r = i >> 12, c = i & 4095;
        *(float4*)&sX[r][c] = *(const float4*)&x[(size_t)(row0 + r) * 4096 + c];
    }
    __syncthreads();
    const float4* wrow = (const float4*)&w[(size_t)col * 4096];
    float a0 = 0.f, a1 = 0.f;
    for (int k4 = 0; k4 < 1024; ++k4) {
        float4 wv = wrow[k4];
        int k = k4 << 2;
        a0 += wv.x * sX[0][k] + wv.y * sX[0][k + 1] + wv.z * sX[0][k + 2] + wv.w * sX[0][k + 3];
        a1 += wv.x * sX[1][k] + wv.y * sX[1][k + 1] + wv.z * sX[1][k + 2] + wv.w * sX[1][k + 3];
    }
    float bv = bias[col];
    out[(size_t)row0 * 4096 + col] = a0 + bv;
    out[(size_t)(row0 + 1) * 4096 + col] = a1 + bv;
}

extern "C" void kernel_launch(void* const* d_in, const int* in_sizes, int n_in,
                              void* d_out, int out_size, void* d_ws, size_t ws_size,
                              hipStream_t stream) {
    const float* x    = (const float*)d_in[0];
    const float* w    = (const float*)d_in[1];
    const float* bias = (const float*)d_in[2];
    float* out = (float*)d_out;

    const size_t nX = (size_t)M_DIM * K_DIM;
    const size_t nW = (size_t)N_DIM * K_DIM;
    const size_t need = (nX + nW) * sizeof(unsigned short);

    if (ws_size >= need) {
        unsigned short* xb = (unsigned short*)d_ws;
        unsigned short* wb = xb + nX;
        cvt_both_f32_to_bf16<<<3072, 256, 0, stream>>>(
            x, w, (unsigned short*)d_ws, (int)(nX / 4), (int)(nW / 4));
        hipError_t e = hipFuncSetAttribute(
            (const void*)gemm_bf16_128x256_bk32,
            hipFuncAttributeMaxDynamicSharedMemorySize, 49152);
        if (e == hipSuccess) {
            gemm_bf16_128x256_bk32<<<(M_DIM / 128) * (N_DIM / 256), 512, 49152, stream>>>(
                xb, wb, bias, out);
        } else {
            gemm_bf16_mfma<<<(M_DIM / 128) * (N_DIM / 128), 256, 0, stream>>>(
                xb, wb, bias, out);
        }
    } else {
        fallback_gemm_f32<<<dim3(N_DIM / 256, M_DIM / 2), 256, 0, stream>>>(x, w, bias, out);
    }
}